// Round 1
// 1300.672 us; speedup vs baseline: 1.0938x; 1.0938x over previous
//
#include <hip/hip_runtime.h>
#include <hip/hip_bf16.h>
#include <cstddef>

#define NN 1024
#define HH 12
#define SQK 16
#define SV 16
#define PQK 4
#define PV 8
#define C1 384
#define C2 128
#define COUT 384

#define HSQK (HH*SQK)            // 192
#define HKV  (HH*(SQK+SV))       // 384
#define QPF  (HH*3*PQK)          // 144
#define KVPF (HH*3*(PQK+PV))     // 432
#define FDIM (HH*(C2+SV+4*PV))   // 2112

__device__ __constant__ const float SCALAR_W  = 0.14433756729740643f; // 1/sqrt(48)
__device__ __constant__ const float POINT_W   = 0.13608276348795434f; // 1/sqrt(54)
__device__ __constant__ const float W2D_SCALE = 0.5773502691896258f;  // 1/sqrt(3)

// ---------------- workspace layout (float offsets) ----------------
constexpr size_t OFF_QS     = 0;                        // 1024*192
constexpr size_t OFF_KVS    = OFF_QS     + 196608;      // 1024*384
constexpr size_t OFF_QPF    = OFF_KVS    + 393216;      // 1024*144
constexpr size_t OFF_KVPF   = OFF_QPF    + 147456;      // 1024*432
constexpr size_t OFF_QPTG   = OFF_KVPF   + 442368;      // 1024*144
constexpr size_t OFF_KVPTG  = OFF_QPTG   + 147456;      // 1024*432
constexpr size_t OFF_Q2     = OFF_KVPTG  + 442368;      // 12*1024
constexpr size_t OFF_K2     = OFF_Q2     + 12288;       // 12*1024
constexpr size_t OFF_PW     = OFF_K2     + 12288;       // 64
constexpr size_t OFF_VT     = OFF_PW     + 64;          // 480*1024
constexpr size_t OFF_RESPTG = OFF_VT     + 491520;      // 1024*288
constexpr size_t OFF_FINAL  = OFF_RESPTG + 294912;      // 1024*2112
constexpr size_t OFF_LOGITS = OFF_FINAL  + 2162688;     // 12*1024*1024
// total = 17,326,144 floats = ~69.3 MB

// ---------------- generic 128x64 fp32 GEMM tile ----------------
template <bool ATOMIC>
__device__ void gemm_tile_128x64(const float* __restrict__ A, const float* __restrict__ W,
                                 const float* __restrict__ bias, float* __restrict__ C,
                                 int K, int Ncols, int m0, int n0, int k0, int ktiles,
                                 bool addbias)
{
    __shared__ float As[16][136]; // padded: rows 544B (16B-aligned), breaks conflicts
    __shared__ float Bs[16][68];  // rows 272B (16B-aligned)
    const int t  = threadIdx.x;
    const int tx = t & 15;   // col group (4 cols)
    const int ty = t >> 4;   // row group (8 rows)

    float acc[8][4];
#pragma unroll
    for (int i = 0; i < 8; ++i)
#pragma unroll
        for (int j = 0; j < 4; ++j) acc[i][j] = 0.f;

    for (int kt = 0; kt < ktiles; ++kt) {
        const int kb = k0 + kt * 16;
        // A tile: 128 rows x 16 k, loaded as 2 x float4 per thread, stored transposed
        {
            const int mi = t >> 1, k8 = (t & 1) * 8;
            const float* src = A + (size_t)(m0 + mi) * K + kb + k8;
            float4 v0 = *(const float4*)(src);
            float4 v1 = *(const float4*)(src + 4);
            As[k8 + 0][mi] = v0.x; As[k8 + 1][mi] = v0.y;
            As[k8 + 2][mi] = v0.z; As[k8 + 3][mi] = v0.w;
            As[k8 + 4][mi] = v1.x; As[k8 + 5][mi] = v1.y;
            As[k8 + 6][mi] = v1.z; As[k8 + 7][mi] = v1.w;
        }
        // B tile: 16 k x 64 cols
        {
            const int kk = t >> 4, n4 = (t & 15) * 4;
            const int col = n0 + n4;
            float4 v = make_float4(0.f, 0.f, 0.f, 0.f);
            if (col < Ncols) v = *(const float4*)(W + (size_t)(kb + kk) * Ncols + col);
            *(float4*)&Bs[kk][n4] = v;
        }
        __syncthreads();
#pragma unroll
        for (int kk = 0; kk < 16; ++kk) {
            float bv[4];
            *(float4*)bv = *(const float4*)&Bs[kk][tx * 4];
            float av[8];
            *(float4*)&av[0] = *(const float4*)&As[kk][ty * 8];
            *(float4*)&av[4] = *(const float4*)&As[kk][ty * 8 + 4];
#pragma unroll
            for (int i = 0; i < 8; ++i)
#pragma unroll
                for (int j = 0; j < 4; ++j) acc[i][j] += av[i] * bv[j];
        }
        __syncthreads();
    }
#pragma unroll
    for (int i = 0; i < 8; ++i) {
        const int row = m0 + ty * 8 + i;
#pragma unroll
        for (int j = 0; j < 4; ++j) {
            const int col = n0 + tx * 4 + j;
            if (col < Ncols) {
                float v = acc[i][j] + (addbias ? bias[col] : 0.f);
                if (ATOMIC) atomicAdd(&C[(size_t)row * Ncols + col], v);
                else        C[(size_t)row * Ncols + col] = v;
            }
        }
    }
}

// ---------------- 1: fused projection GEMMs ----------------
__global__ __launch_bounds__(256) void proj_kernel(
    const float* __restrict__ A,
    const float* __restrict__ wqs,  const float* __restrict__ bqs,
    const float* __restrict__ wkvs, const float* __restrict__ bkvs,
    const float* __restrict__ wqp,  const float* __restrict__ bqp,
    const float* __restrict__ wkvp, const float* __restrict__ bkvp,
    float* __restrict__ qs, float* __restrict__ kvs,
    float* __restrict__ qpf, float* __restrict__ kvpf)
{
    const int ct = blockIdx.x % 19;
    const int mt = blockIdx.x / 19;
    const float *W, *bias; float* C; int Ncols, n0;
    if (ct < 3)       { W = wqs;  bias = bqs;  C = qs;   Ncols = 192; n0 = ct * 64; }
    else if (ct < 9)  { W = wkvs; bias = bkvs; C = kvs;  Ncols = 384; n0 = (ct - 3) * 64; }
    else if (ct < 12) { W = wqp;  bias = bqp;  C = qpf;  Ncols = 144; n0 = (ct - 9) * 64; }
    else              { W = wkvp; bias = bkvp; C = kvpf; Ncols = 432; n0 = (ct - 12) * 64; }
    gemm_tile_128x64<false>(A, W, bias, C, C1, Ncols, mt * 128, n0, 0, 24, true);
}

// ---------------- 2: point transform, q2/k2, pw ----------------
__global__ __launch_bounds__(192) void points_kernel(
    const float* __restrict__ qpf, const float* __restrict__ kvpf,
    const float* __restrict__ rot, const float* __restrict__ trans,
    const float* __restrict__ tpw,
    float* __restrict__ qptg, float* __restrict__ kvptg,
    float* __restrict__ q2, float* __restrict__ k2, float* __restrict__ pw)
{
    __shared__ float lq[48 * 3];
    __shared__ float lkv[144 * 3];
    const int n = blockIdx.x, t = threadIdx.x;
    float r[9], tr[3];
#pragma unroll
    for (int i = 0; i < 9; ++i) r[i] = rot[n * 9 + i];
#pragma unroll
    for (int i = 0; i < 3; ++i) tr[i] = trans[n * 3 + i];

    if (t < 48) {
        float p0 = qpf[n * QPF + t], p1 = qpf[n * QPF + 48 + t], p2 = qpf[n * QPF + 96 + t];
#pragma unroll
        for (int i = 0; i < 3; ++i)
            lq[t * 3 + i] = r[i * 3 + 0] * p0 + r[i * 3 + 1] * p1 + r[i * 3 + 2] * p2 + tr[i];
    }
    if (t < 144) {
        float p0 = kvpf[(size_t)n * KVPF + t];
        float p1 = kvpf[(size_t)n * KVPF + 144 + t];
        float p2 = kvpf[(size_t)n * KVPF + 288 + t];
#pragma unroll
        for (int i = 0; i < 3; ++i)
            lkv[t * 3 + i] = r[i * 3 + 0] * p0 + r[i * 3 + 1] * p1 + r[i * 3 + 2] * p2 + tr[i];
    }
    __syncthreads();
    if (t < 48) {
#pragma unroll
        for (int i = 0; i < 3; ++i) qptg[(size_t)n * QPF + t * 3 + i] = lq[t * 3 + i];
    }
    if (t < 144) {
#pragma unroll
        for (int i = 0; i < 3; ++i) kvptg[(size_t)n * KVPF + t * 3 + i] = lkv[t * 3 + i];
    }
    if (t < HH) {
        float s = 0.f;
#pragma unroll
        for (int p = 0; p < 4; ++p)
#pragma unroll
            for (int i = 0; i < 3; ++i) { float v = lq[(t * 4 + p) * 3 + i]; s += v * v; }
        q2[t * NN + n] = s;
        float s2 = 0.f;
#pragma unroll
        for (int p = 0; p < 4; ++p)
#pragma unroll
            for (int i = 0; i < 3; ++i) { float v = lkv[(t * 12 + p) * 3 + i]; s2 += v * v; }
        k2[t * NN + n] = s2;
        if (n == 0) {
            float x = tpw[t];
            float sp = (x > 20.f) ? x : log1pf(__expf(x));
            pw[t] = sp * POINT_W;
        }
    }
}

// ---------------- 3: build transposed V table (480 x 1024) ----------------
__global__ __launch_bounds__(256) void vt_kernel(const float* __restrict__ kvs,
                                                 const float* __restrict__ kvptg,
                                                 float* __restrict__ vT)
{
    const int idx = blockIdx.x * 256 + threadIdx.x;  // 480*1024 total
    const int r = idx >> 10, m = idx & 1023;
    float val;
    if (r < 192) {
        const int h = r >> 4, c = r & 15;
        val = kvs[(size_t)m * HKV + h * 32 + 16 + c];
    } else {
        const int q = r - 192;
        const int h = q / 24, rem = q % 24;
        val = kvptg[(size_t)m * KVPF + h * 36 + 12 + rem];
    }
    vT[(size_t)r * NN + m] = val;
}

// ---------------- 4a: a2d + bias + mask -> logits init (coalesced stream of in2d) ----
// Block: one n, 64 m's. Load 64x128 in2d tile coalesced, transpose in LDS, compute
// 12 head-dots, write logits[h][n][m] = W2D_SCALE*(a2d+b2d) + mval.
__global__ __launch_bounds__(256) void a2d_kernel(
    const float* __restrict__ in2d, const float* __restrict__ w2d,
    const float* __restrict__ b2d, const float* __restrict__ mask,
    float* __restrict__ logits)
{
    __shared__ float As[128 * 65];      // As[c*65 + r], transposed, pad 65
    __shared__ float w2s[C2 * HH];      // 6 KB
    __shared__ float red[4][64][13];    // partials per c-quarter, pad 13
    const int t  = threadIdx.x;
    const int n  = blockIdx.y;
    const int m0 = blockIdx.x * 64;

    for (int i = t; i < C2 * HH; i += 256) w2s[i] = w2d[i];

    // coalesced load: lane groups of 8 cover 8 rows at consecutive 16B chunks
    const int rl = t & 7;       // row within 8-row slab
    const int c4 = t >> 3;      // 0..31 float4 column
    const float* base = in2d + ((size_t)n * NN + m0) * C2;
    float4 v[8];
#pragma unroll
    for (int it = 0; it < 8; ++it)
        v[it] = *(const float4*)(base + (size_t)(it * 8 + rl) * C2 + c4 * 4);
#pragma unroll
    for (int it = 0; it < 8; ++it) {
        const int r = it * 8 + rl;
        As[(c4 * 4 + 0) * 65 + r] = v[it].x;
        As[(c4 * 4 + 1) * 65 + r] = v[it].y;
        As[(c4 * 4 + 2) * 65 + r] = v[it].z;
        As[(c4 * 4 + 3) * 65 + r] = v[it].w;
    }
    __syncthreads();

    // partial dots: thread = (row r, c-quarter cq)
    {
        const int r  = t & 63;
        const int cq = t >> 6;
        float acc[HH];
#pragma unroll
        for (int h = 0; h < HH; ++h) acc[h] = 0.f;
        const int cbeg = cq * 32;
#pragma unroll 8
        for (int ci = 0; ci < 32; ++ci) {
            const int c = cbeg + ci;
            const float a = As[c * 65 + r];
            const float* w = &w2s[c * HH];
#pragma unroll
            for (int h = 0; h < HH; ++h) acc[h] += a * w[h];
        }
#pragma unroll
        for (int h = 0; h < HH; ++h) red[cq][r][h] = acc[h];
    }
    __syncthreads();

    // final: thread = (row r2, head-triple)
    {
        const int r2 = t & 63;
        const int hb = (t >> 6) * 3;
        const float mval = -100000.f * (1.f - mask[n] * mask[m0 + r2]);
#pragma unroll
        for (int j = 0; j < 3; ++j) {
            const int h = hb + j;
            const float s = red[0][r2][h] + red[1][r2][h] + red[2][r2][h] + red[3][r2][h];
            logits[((size_t)h * NN + n) * NN + m0 + r2] = W2D_SCALE * (s + b2d[h]) + mval;
        }
    }
}

// ---------------- 4b: QK logits as rank-30 GEMM per head, += into logits ----------
// qt = [SCALAR_W*q_scalar(16), pw*q_pt(12), -0.5*pw*q2, 1]
// kt = [k_scalar(16),          k_pt(12),    1,          -0.5*pw*k2]
// logits[h][n][m] += dot(qt, kt)
__global__ __launch_bounds__(256) void qk_kernel(
    const float* __restrict__ qs, const float* __restrict__ kvs,
    const float* __restrict__ qptg, const float* __restrict__ kvptg,
    const float* __restrict__ q2, const float* __restrict__ k2,
    const float* __restrict__ pw, float* __restrict__ logits)
{
    __shared__ float qT[30][132];   // [c][n-local], pad 132
    __shared__ float kT[30][132];   // [c][m-local]
    const int t  = threadIdx.x;
    const int h  = blockIdx.x;
    const int n0 = blockIdx.y * 128;
    const int m0 = blockIdx.z * 128;
    const float pwh = pw[h];

    // ---- stage q (transposed, scaled) ----
    for (int i = t; i < 512; i += 256) {          // scalar: 128 rows x 4 f4
        const int nl = i >> 2, cq = i & 3;
        float4 a = *(const float4*)(qs + (size_t)(n0 + nl) * HSQK + h * SQK + cq * 4);
        qT[4 * cq + 0][nl] = SCALAR_W * a.x;
        qT[4 * cq + 1][nl] = SCALAR_W * a.y;
        qT[4 * cq + 2][nl] = SCALAR_W * a.z;
        qT[4 * cq + 3][nl] = SCALAR_W * a.w;
    }
    for (int i = t; i < 384; i += 256) {          // point: 128 rows x 3 f4
        const int nl = i / 3, c3 = i - nl * 3;
        float4 a = *(const float4*)(qptg + (size_t)(n0 + nl) * QPF + h * 3 * PQK + c3 * 4);
        qT[16 + 4 * c3 + 0][nl] = pwh * a.x;
        qT[16 + 4 * c3 + 1][nl] = pwh * a.y;
        qT[16 + 4 * c3 + 2][nl] = pwh * a.z;
        qT[16 + 4 * c3 + 3][nl] = pwh * a.w;
    }
    if (t < 128) {
        qT[28][t] = -0.5f * pwh * q2[(size_t)h * NN + n0 + t];
        qT[29][t] = 1.f;
    }
    // ---- stage k (transposed, unscaled) ----
    for (int i = t; i < 512; i += 256) {
        const int ml = i >> 2, cq = i & 3;
        float4 a = *(const float4*)(kvs + (size_t)(m0 + ml) * HKV + h * (SQK + SV) + cq * 4);
        kT[4 * cq + 0][ml] = a.x;
        kT[4 * cq + 1][ml] = a.y;
        kT[4 * cq + 2][ml] = a.z;
        kT[4 * cq + 3][ml] = a.w;
    }
    for (int i = t; i < 384; i += 256) {
        const int ml = i / 3, c3 = i - ml * 3;
        float4 a = *(const float4*)(kvptg + (size_t)(m0 + ml) * KVPF + h * 3 * (PQK + PV) + c3 * 4);
        kT[16 + 4 * c3 + 0][ml] = a.x;
        kT[16 + 4 * c3 + 1][ml] = a.y;
        kT[16 + 4 * c3 + 2][ml] = a.z;
        kT[16 + 4 * c3 + 3][ml] = a.w;
    }
    if (t < 128) {
        kT[28][t] = 1.f;
        kT[29][t] = -0.5f * pwh * k2[(size_t)h * NN + m0 + t];
    }
    __syncthreads();

    // ---- 128x128 tile: thread = (tn: 8 n-rows, tm: two 4-col chunks 64 apart) ----
    const int tn = t >> 4;   // 0..15 -> n rows tn*8..tn*8+7
    const int tm = t & 15;   // cols tm*4..+3 and 64+tm*4..+3
    float acc[8][8];
#pragma unroll
    for (int i = 0; i < 8; ++i)
#pragma unroll
        for (int j = 0; j < 8; ++j) acc[i][j] = 0.f;

    for (int c = 0; c < 30; ++c) {
        float qv[8], kv[8];
        *(float4*)&qv[0] = *(const float4*)&qT[c][tn * 8];
        *(float4*)&qv[4] = *(const float4*)&qT[c][tn * 8 + 4];
        *(float4*)&kv[0] = *(const float4*)&kT[c][tm * 4];
        *(float4*)&kv[4] = *(const float4*)&kT[c][64 + tm * 4];
#pragma unroll
        for (int i = 0; i < 8; ++i)
#pragma unroll
            for (int j = 0; j < 8; ++j) acc[i][j] += qv[i] * kv[j];
    }

    // ---- RMW epilogue ----
#pragma unroll
    for (int i = 0; i < 8; ++i) {
        float* lg = logits + ((size_t)h * NN + n0 + tn * 8 + i) * NN + m0;
        float4* p0 = (float4*)(lg + tm * 4);
        float4* p1 = (float4*)(lg + 64 + tm * 4);
        float4 a = *p0, b = *p1;
        a.x += acc[i][0]; a.y += acc[i][1]; a.z += acc[i][2]; a.w += acc[i][3];
        b.x += acc[i][4]; b.y += acc[i][5]; b.z += acc[i][6]; b.w += acc[i][7];
        *p0 = a; *p1 = b;
    }
}

// ---------------- 5: row softmax in place ----------------
__global__ __launch_bounds__(256) void softmax_kernel(float* __restrict__ logits)
{
    const size_t rowid = blockIdx.x; // h*N + n
    float* p = logits + rowid * NN;
    const int t = threadIdx.x;
    float4 v = ((float4*)p)[t];
    float mx = fmaxf(fmaxf(v.x, v.y), fmaxf(v.z, v.w));
#pragma unroll
    for (int o = 32; o; o >>= 1) mx = fmaxf(mx, __shfl_xor(mx, o));
    __shared__ float redm[4];
    __shared__ float reds[4];
    const int w = t >> 6, lane = t & 63;
    if (lane == 0) redm[w] = mx;
    __syncthreads();
    mx = fmaxf(fmaxf(redm[0], redm[1]), fmaxf(redm[2], redm[3]));
    float e0 = __expf(v.x - mx), e1 = __expf(v.y - mx), e2 = __expf(v.z - mx), e3 = __expf(v.w - mx);
    float s = e0 + e1 + e2 + e3;
#pragma unroll
    for (int o = 32; o; o >>= 1) s += __shfl_xor(s, o);
    if (lane == 0) reds[w] = s;
    __syncthreads();
    s = reds[0] + reds[1] + reds[2] + reds[3];
    const float inv = 1.f / s;
    ((float4*)p)[t] = make_float4(e0 * inv, e1 * inv, e2 * inv, e3 * inv);
}

// ---------------- 6: attn_2d (second inputs_2d pass) ----------------
__global__ __launch_bounds__(256) void attn2d_kernel(
    const float* __restrict__ attn, const float* __restrict__ in2d, float* __restrict__ fin)
{
    __shared__ float la[NN * HH]; // [m][h] 48 KB
    const int t = threadIdx.x;
    const int n = blockIdx.x;
#pragma unroll
    for (int h = 0; h < HH; ++h)
#pragma unroll
        for (int k = 0; k < 4; ++k) {
            const int m = t + (k << 8);
            la[m * HH + h] = attn[((size_t)h * NN + n) * NN + m];
        }
    __syncthreads();

    const int c0 = t & 31;
    const int ml = t >> 5; // 0..7
    float acc[HH][4];
#pragma unroll
    for (int h = 0; h < HH; ++h)
#pragma unroll
        for (int j = 0; j < 4; ++j) acc[h][j] = 0.f;

    const float* base = in2d + (size_t)n * NN * C2;
    for (int m = ml; m < NN; m += 8) {
        const float* r2 = base + (size_t)m * C2;
        float v0 = r2[c0], v1 = r2[c0 + 32], v2 = r2[c0 + 64], v3 = r2[c0 + 96];
        const float* am = &la[m * HH];
        float av[HH];
        *(float4*)&av[0] = *(const float4*)(am);
        *(float4*)&av[4] = *(const float4*)(am + 4);
        *(float4*)&av[8] = *(const float4*)(am + 8);
#pragma unroll
        for (int h = 0; h < HH; ++h) {
            acc[h][0] += av[h] * v0; acc[h][1] += av[h] * v1;
            acc[h][2] += av[h] * v2; acc[h][3] += av[h] * v3;
        }
    }
    // reduce 8 m-lanes per (h, c); reuse la as [8][128] scratch
    for (int h = 0; h < HH; ++h) {
        __syncthreads();
        la[(ml << 7) + c0]      = acc[h][0];
        la[(ml << 7) + c0 + 32] = acc[h][1];
        la[(ml << 7) + c0 + 64] = acc[h][2];
        la[(ml << 7) + c0 + 96] = acc[h][3];
        __syncthreads();
        if (t < 128) {
            float s = 0.f;
#pragma unroll
            for (int l = 0; l < 8; ++l) s += la[(l << 7) + t];
            fin[(size_t)n * FDIM + 576 + (h << 7) + t] = s;
        }
    }
}

// ---------------- 7: attn @ V (scalar + points, via transposed V) ----------------
__global__ __launch_bounds__(256) void attnv_kernel(
    const float* __restrict__ attn, const float* __restrict__ vT,
    float* __restrict__ fin, float* __restrict__ resptg)
{
    __shared__ float la[HH * 1040]; // [h][m], padded row 1040 (16B-aligned, conflict-free)
    const int t = threadIdx.x;
    const int n = blockIdx.x;
#pragma unroll
    for (int h = 0; h < HH; ++h)
#pragma unroll
        for (int k = 0; k < 4; ++k) {
            const int m = t + (k << 8);
            la[h * 1040 + m] = attn[((size_t)h * NN + n) * NN + m];
        }
    __syncthreads();
    for (int r = t; r < 480; r += 256) {
        const int h = (r < 192) ? (r >> 4) : ((r - 192) / 24);
        const float4* vr = (const float4*)(vT + (size_t)r * NN);
        const float4* ar = (const float4*)&la[h * 1040];
        float s = 0.f;
        for (int q = 0; q < NN / 4; ++q) {
            float4 a = ar[q], v = vr[q];
            s += a.x * v.x + a.y * v.y + a.z * v.z + a.w * v.w;
        }
        if (r < 192) fin[(size_t)n * FDIM + r] = s;
        else         resptg[(size_t)n * 288 + (r - 192)] = s;
    }
}

// ---------------- 8: invert point transform, dist, write into final ----------------
__global__ __launch_bounds__(128) void ptout_kernel(
    const float* __restrict__ resptg, const float* __restrict__ rot,
    const float* __restrict__ trans, float* __restrict__ fin)
{
    const int n = blockIdx.x, t = threadIdx.x;
    if (t >= 96) return;
    float g0 = resptg[(size_t)n * 288 + t * 3 + 0];
    float g1 = resptg[(size_t)n * 288 + t * 3 + 1];
    float g2 = resptg[(size_t)n * 288 + t * 3 + 2];
    float d0 = g0 - trans[n * 3 + 0];
    float d1 = g1 - trans[n * 3 + 1];
    float d2 = g2 - trans[n * 3 + 2];
    // l_i = sum_j rot[j][i] * d[j]  (R^T d)
    float l0 = rot[n * 9 + 0] * d0 + rot[n * 9 + 3] * d1 + rot[n * 9 + 6] * d2;
    float l1 = rot[n * 9 + 1] * d0 + rot[n * 9 + 4] * d1 + rot[n * 9 + 7] * d2;
    float l2 = rot[n * 9 + 2] * d0 + rot[n * 9 + 5] * d1 + rot[n * 9 + 8] * d2;
    const size_t base = (size_t)n * FDIM;
    fin[base + 192 + t] = l0;
    fin[base + 288 + t] = l1;
    fin[base + 384 + t] = l2;
    fin[base + 480 + t] = sqrtf(1e-8f + l0 * l0 + l1 * l1 + l2 * l2);
}

// ---------------- 9: final GEMM (K-split + atomics) ----------------
__global__ __launch_bounds__(256) void outgemm_kernel(
    const float* __restrict__ fin, const float* __restrict__ wout,
    const float* __restrict__ bout, float* __restrict__ out)
{
    const int n0 = blockIdx.x * 64;
    const int m0 = blockIdx.y * 128;
    const int z  = blockIdx.z;
    gemm_tile_128x64<true>(fin, wout, bout, out, FDIM, COUT, m0, n0, z * 352, 22, z == 0);
}

extern "C" void kernel_launch(void* const* d_in, const int* in_sizes, int n_in,
                              void* d_out, int out_size, void* d_ws, size_t ws_size,
                              hipStream_t stream)
{
    const float* in1d  = (const float*)d_in[0];
    const float* in2d  = (const float*)d_in[1];
    const float* mask  = (const float*)d_in[2];
    const float* rot   = (const float*)d_in[3];
    const float* trans = (const float*)d_in[4];
    const float* wqs   = (const float*)d_in[5];
    const float* bqs   = (const float*)d_in[6];
    const float* wkvs  = (const float*)d_in[7];
    const float* bkvs  = (const float*)d_in[8];
    const float* wqp   = (const float*)d_in[9];
    const float* bqp   = (const float*)d_in[10];
    const float* bkvpW = (const float*)d_in[11]; // w_kv_point
    const float* bkvpB = (const float*)d_in[12]; // b_kv_point
    const float* w2d   = (const float*)d_in[13];
    const float* b2d   = (const float*)d_in[14];
    const float* tpw   = (const float*)d_in[15];
    const float* wout  = (const float*)d_in[16];
    const float* bout  = (const float*)d_in[17];

    float* ws     = (float*)d_ws;
    float* qs     = ws + OFF_QS;
    float* kvs    = ws + OFF_KVS;
    float* qpf    = ws + OFF_QPF;
    float* kvpf   = ws + OFF_KVPF;
    float* qptg   = ws + OFF_QPTG;
    float* kvptg  = ws + OFF_KVPTG;
    float* q2     = ws + OFF_Q2;
    float* k2     = ws + OFF_K2;
    float* pw     = ws + OFF_PW;
    float* vT     = ws + OFF_VT;
    float* resptg = ws + OFF_RESPTG;
    float* fin    = ws + OFF_FINAL;
    float* logits = ws + OFF_LOGITS;

    // output accumulated atomically by the K-split final GEMM -> zero it first
    hipMemsetAsync(d_out, 0, (size_t)out_size * sizeof(float), stream);

    proj_kernel<<<152, 256, 0, stream>>>(in1d, wqs, bqs, wkvs, bkvs, wqp, bqp, bkvpW, bkvpB,
                                         qs, kvs, qpf, kvpf);
    points_kernel<<<NN, 192, 0, stream>>>(qpf, kvpf, rot, trans, tpw, qptg, kvptg, q2, k2, pw);
    vt_kernel<<<1920, 256, 0, stream>>>(kvs, kvptg, vT);
    a2d_kernel<<<dim3(16, NN), 256, 0, stream>>>(in2d, w2d, b2d, mask, logits);
    qk_kernel<<<dim3(HH, 8, 8), 256, 0, stream>>>(qs, kvs, qptg, kvptg, q2, k2, pw, logits);
    softmax_kernel<<<HH * NN, 256, 0, stream>>>(logits);
    attn2d_kernel<<<NN, 256, 0, stream>>>(logits, in2d, fin);
    attnv_kernel<<<NN, 256, 0, stream>>>(logits, vT, fin, resptg);
    ptout_kernel<<<NN, 128, 0, stream>>>(resptg, rot, trans, fin);
    outgemm_kernel<<<dim3(6, 8, 6), 256, 0, stream>>>(fin, wout, bout, (float*)d_out);
}

// Round 2
// 1186.448 us; speedup vs baseline: 1.1991x; 1.0963x over previous
//
#include <hip/hip_runtime.h>
#include <hip/hip_bf16.h>
#include <cstddef>

#define NN 1024
#define HH 12
#define SQK 16
#define SV 16
#define PQK 4
#define PV 8
#define C1 384
#define C2 128
#define COUT 384

#define HSQK (HH*SQK)            // 192
#define HKV  (HH*(SQK+SV))       // 384
#define QPF  (HH*3*PQK)          // 144
#define KVPF (HH*3*(PQK+PV))     // 432
#define FDIM (HH*(C2+SV+4*PV))   // 2112

__device__ __constant__ const float SCALAR_W  = 0.14433756729740643f; // 1/sqrt(48)
__device__ __constant__ const float POINT_W   = 0.13608276348795434f; // 1/sqrt(54)
__device__ __constant__ const float W2D_SCALE = 0.5773502691896258f;  // 1/sqrt(3)

// ---------------- workspace layout (float offsets) ----------------
constexpr size_t OFF_QS     = 0;                        // 1024*192
constexpr size_t OFF_KVS    = OFF_QS     + 196608;      // 1024*384
constexpr size_t OFF_QPF    = OFF_KVS    + 393216;      // 1024*144
constexpr size_t OFF_KVPF   = OFF_QPF    + 147456;      // 1024*432
constexpr size_t OFF_QPTG   = OFF_KVPF   + 442368;      // 1024*144
constexpr size_t OFF_KVPTG  = OFF_QPTG   + 147456;      // 1024*432
constexpr size_t OFF_Q2     = OFF_KVPTG  + 442368;      // 12*1024
constexpr size_t OFF_K2     = OFF_Q2     + 12288;       // 12*1024
constexpr size_t OFF_PW     = OFF_K2     + 12288;       // 64
constexpr size_t OFF_VT     = OFF_PW     + 64;          // 480*1024
constexpr size_t OFF_RESPTG = OFF_VT     + 491520;      // 1024*288
constexpr size_t OFF_FINAL  = OFF_RESPTG + 294912;      // 1024*2112
constexpr size_t OFF_LOGITS = OFF_FINAL  + 2162688;     // 12*1024*1024 (attn)
constexpr size_t OFF_KTAB   = OFF_LOGITS + 12582912;    // 12*1024*32
// total = 17,719,360 floats = ~70.9 MB

// ---------------- generic 128x64 fp32 GEMM tile ----------------
template <bool ATOMIC>
__device__ void gemm_tile_128x64(const float* __restrict__ A, const float* __restrict__ W,
                                 const float* __restrict__ bias, float* __restrict__ C,
                                 int K, int Ncols, int m0, int n0, int k0, int ktiles,
                                 bool addbias)
{
    __shared__ float As[16][136];
    __shared__ float Bs[16][68];
    const int t  = threadIdx.x;
    const int tx = t & 15;
    const int ty = t >> 4;

    float acc[8][4];
#pragma unroll
    for (int i = 0; i < 8; ++i)
#pragma unroll
        for (int j = 0; j < 4; ++j) acc[i][j] = 0.f;

    for (int kt = 0; kt < ktiles; ++kt) {
        const int kb = k0 + kt * 16;
        {
            const int mi = t >> 1, k8 = (t & 1) * 8;
            const float* src = A + (size_t)(m0 + mi) * K + kb + k8;
            float4 v0 = *(const float4*)(src);
            float4 v1 = *(const float4*)(src + 4);
            As[k8 + 0][mi] = v0.x; As[k8 + 1][mi] = v0.y;
            As[k8 + 2][mi] = v0.z; As[k8 + 3][mi] = v0.w;
            As[k8 + 4][mi] = v1.x; As[k8 + 5][mi] = v1.y;
            As[k8 + 6][mi] = v1.z; As[k8 + 7][mi] = v1.w;
        }
        {
            const int kk = t >> 4, n4 = (t & 15) * 4;
            const int col = n0 + n4;
            float4 v = make_float4(0.f, 0.f, 0.f, 0.f);
            if (col < Ncols) v = *(const float4*)(W + (size_t)(kb + kk) * Ncols + col);
            *(float4*)&Bs[kk][n4] = v;
        }
        __syncthreads();
#pragma unroll
        for (int kk = 0; kk < 16; ++kk) {
            float bv[4];
            *(float4*)bv = *(const float4*)&Bs[kk][tx * 4];
            float av[8];
            *(float4*)&av[0] = *(const float4*)&As[kk][ty * 8];
            *(float4*)&av[4] = *(const float4*)&As[kk][ty * 8 + 4];
#pragma unroll
            for (int i = 0; i < 8; ++i)
#pragma unroll
                for (int j = 0; j < 4; ++j) acc[i][j] += av[i] * bv[j];
        }
        __syncthreads();
    }
#pragma unroll
    for (int i = 0; i < 8; ++i) {
        const int row = m0 + ty * 8 + i;
#pragma unroll
        for (int j = 0; j < 4; ++j) {
            const int col = n0 + tx * 4 + j;
            if (col < Ncols) {
                float v = acc[i][j] + (addbias ? bias[col] : 0.f);
                if (ATOMIC) atomicAdd(&C[(size_t)row * Ncols + col], v);
                else        C[(size_t)row * Ncols + col] = v;
            }
        }
    }
}

// ---------------- 1: fused projection GEMMs ----------------
__global__ __launch_bounds__(256) void proj_kernel(
    const float* __restrict__ A,
    const float* __restrict__ wqs,  const float* __restrict__ bqs,
    const float* __restrict__ wkvs, const float* __restrict__ bkvs,
    const float* __restrict__ wqp,  const float* __restrict__ bqp,
    const float* __restrict__ wkvp, const float* __restrict__ bkvp,
    float* __restrict__ qs, float* __restrict__ kvs,
    float* __restrict__ qpf, float* __restrict__ kvpf)
{
    const int ct = blockIdx.x % 19;
    const int mt = blockIdx.x / 19;
    const float *W, *bias; float* C; int Ncols, n0;
    if (ct < 3)       { W = wqs;  bias = bqs;  C = qs;   Ncols = 192; n0 = ct * 64; }
    else if (ct < 9)  { W = wkvs; bias = bkvs; C = kvs;  Ncols = 384; n0 = (ct - 3) * 64; }
    else if (ct < 12) { W = wqp;  bias = bqp;  C = qpf;  Ncols = 144; n0 = (ct - 9) * 64; }
    else              { W = wkvp; bias = bkvp; C = kvpf; Ncols = 432; n0 = (ct - 12) * 64; }
    gemm_tile_128x64<false>(A, W, bias, C, C1, Ncols, mt * 128, n0, 0, 24, true);
}

// ---------------- 2: point transform, q2/k2, pw ----------------
__global__ __launch_bounds__(192) void points_kernel(
    const float* __restrict__ qpf, const float* __restrict__ kvpf,
    const float* __restrict__ rot, const float* __restrict__ trans,
    const float* __restrict__ tpw,
    float* __restrict__ qptg, float* __restrict__ kvptg,
    float* __restrict__ q2, float* __restrict__ k2, float* __restrict__ pw)
{
    __shared__ float lq[48 * 3];
    __shared__ float lkv[144 * 3];
    const int n = blockIdx.x, t = threadIdx.x;
    float r[9], tr[3];
#pragma unroll
    for (int i = 0; i < 9; ++i) r[i] = rot[n * 9 + i];
#pragma unroll
    for (int i = 0; i < 3; ++i) tr[i] = trans[n * 3 + i];

    if (t < 48) {
        float p0 = qpf[n * QPF + t], p1 = qpf[n * QPF + 48 + t], p2 = qpf[n * QPF + 96 + t];
#pragma unroll
        for (int i = 0; i < 3; ++i)
            lq[t * 3 + i] = r[i * 3 + 0] * p0 + r[i * 3 + 1] * p1 + r[i * 3 + 2] * p2 + tr[i];
    }
    if (t < 144) {
        float p0 = kvpf[(size_t)n * KVPF + t];
        float p1 = kvpf[(size_t)n * KVPF + 144 + t];
        float p2 = kvpf[(size_t)n * KVPF + 288 + t];
#pragma unroll
        for (int i = 0; i < 3; ++i)
            lkv[t * 3 + i] = r[i * 3 + 0] * p0 + r[i * 3 + 1] * p1 + r[i * 3 + 2] * p2 + tr[i];
    }
    __syncthreads();
    if (t < 48) {
#pragma unroll
        for (int i = 0; i < 3; ++i) qptg[(size_t)n * QPF + t * 3 + i] = lq[t * 3 + i];
    }
    if (t < 144) {
#pragma unroll
        for (int i = 0; i < 3; ++i) kvptg[(size_t)n * KVPF + t * 3 + i] = lkv[t * 3 + i];
    }
    if (t < HH) {
        float s = 0.f;
#pragma unroll
        for (int p = 0; p < 4; ++p)
#pragma unroll
            for (int i = 0; i < 3; ++i) { float v = lq[(t * 4 + p) * 3 + i]; s += v * v; }
        q2[t * NN + n] = s;
        float s2 = 0.f;
#pragma unroll
        for (int p = 0; p < 4; ++p)
#pragma unroll
            for (int i = 0; i < 3; ++i) { float v = lkv[(t * 12 + p) * 3 + i]; s2 += v * v; }
        k2[t * NN + n] = s2;
        if (n == 0) {
            float x = tpw[t];
            float sp = (x > 20.f) ? x : log1pf(__expf(x));
            pw[t] = sp * POINT_W;
        }
    }
}

// ---------------- 3: build transposed V table (480 x 1024) ----------------
__global__ __launch_bounds__(256) void vt_kernel(const float* __restrict__ kvs,
                                                 const float* __restrict__ kvptg,
                                                 float* __restrict__ vT)
{
    const int idx = blockIdx.x * 256 + threadIdx.x;  // 480*1024 total
    const int r = idx >> 10, m = idx & 1023;
    float val;
    if (r < 192) {
        const int h = r >> 4, c = r & 15;
        val = kvs[(size_t)m * HKV + h * 32 + 16 + c];
    } else {
        const int q = r - 192;
        const int h = q / 24, rem = q % 24;
        val = kvptg[(size_t)m * KVPF + h * 36 + 12 + rem];
    }
    vT[(size_t)r * NN + m] = val;
}

// ---------------- 3b: build k-tilde table ktabT[12][1024][32] ----------------
// k~ = [k_scalar(16), k_pt(12), 1, -0.5*pw*k2, 1, 0]
// matching q~ = [SCALAR_W*q_s, pw*q_pt, -0.5*pw*q2, 1, W2D*b2d, 0]
__global__ __launch_bounds__(256) void tab_kernel(
    const float* __restrict__ kvs, const float* __restrict__ kvptg,
    const float* __restrict__ k2, const float* __restrict__ pw,
    float* __restrict__ ktab)
{
    const int id = blockIdx.x * 256 + threadIdx.x;   // 0..12287
    const int h = id >> 10, m = id & 1023;
    float v[32];
    const float4* ks = (const float4*)(kvs + (size_t)m * HKV + h * 32);
#pragma unroll
    for (int j = 0; j < 4; ++j) *(float4*)&v[j * 4] = ks[j];
    const float4* kp = (const float4*)(kvptg + (size_t)m * KVPF + h * 36);
#pragma unroll
    for (int j = 0; j < 3; ++j) *(float4*)&v[16 + j * 4] = kp[j];
    v[28] = 1.f;
    v[29] = -0.5f * pw[h] * k2[(size_t)h * NN + m];
    v[30] = 1.f;
    v[31] = 0.f;
    float4* dst = (float4*)(ktab + (size_t)id * 32);
#pragma unroll
    for (int j = 0; j < 8; ++j) dst[j] = *(const float4*)&v[j * 4];
}

// ---------------- 4: FUSED a2d + qk + online-softmax + attn_2d ----------------
// One block per n (512 threads). Streams in2d[n] slab once in 32-row chunks.
// Raw logits kept in LDS (48KB) -> no stored-value rescaling; online max only
// rescales the register-resident attn_2d accumulators. Writes normalized attn
// (for the V GEMM) and the attn_2d block of fin.
__global__ __launch_bounds__(512) void fused_kernel(
    const float* __restrict__ in2d, const float* __restrict__ w2d,
    const float* __restrict__ b2d, const float* __restrict__ mask,
    const float* __restrict__ qs, const float* __restrict__ qptg,
    const float* __restrict__ q2, const float* __restrict__ pw,
    const float* __restrict__ ktab,
    float* __restrict__ attn, float* __restrict__ fin)
{
    __shared__ __align__(16) float pL[12 * 1024];   // raw logits, 48 KB
    __shared__ float xsT[128 * 33];                 // in2d chunk [c][m], 16.5 KB
    __shared__ __align__(16) float w2sT[12 * 128];  // W2D_SCALE * w2d^T
    __shared__ __align__(16) float qt[12 * 32];     // q-tilde
    __shared__ float pe[12 * 32];                   // exp of current chunk
    __shared__ float maskc[32];
    __shared__ float st_m[12], st_s[12], resc[12];

    const int n = blockIdx.x, t = threadIdx.x;

    for (int i = t; i < 1536; i += 512) {
        const int h = i >> 7, c = i & 127;
        w2sT[i] = W2D_SCALE * w2d[c * HH + h];
    }
    if (t < 384) {
        const int h = t >> 5, j = t & 31;
        float v;
        if (j < 16)       v = SCALAR_W * qs[(size_t)n * HSQK + h * 16 + j];
        else if (j < 28)  v = pw[h] * qptg[(size_t)n * QPF + h * 12 + (j - 16)];
        else if (j == 28) v = -0.5f * pw[h] * q2[(size_t)h * NN + n];
        else if (j == 29) v = 1.f;
        else if (j == 30) v = W2D_SCALE * b2d[h];
        else              v = 0.f;
        qt[t] = v;
    }
    if (t < 12) { st_m[t] = -3.0e38f; st_s[t] = 0.f; resc[t] = 0.f; }
    const float maskn = mask[n];
    const int hx = t >> 7, cx = t & 127;   // attn_2d accumulator ownership
    float xa0 = 0.f, xa1 = 0.f, xa2 = 0.f; // heads hx, hx+4, hx+8 at col cx
    __syncthreads();

    for (int mc = 0; mc < 32; ++mc) {
        const int m0 = mc * 32;
        // --- load 32x128 in2d chunk, transposed to [c][m] (conflict-free both phases)
        const float* src = in2d + ((size_t)n * NN + m0) * C2;
#pragma unroll
        for (int k2_ = 0; k2_ < 2; ++k2_) {
            const int f = t + (k2_ << 9);
            const int row = f >> 5, c4 = f & 31;
            float4 v = *(const float4*)(src + (size_t)row * C2 + c4 * 4);
            xsT[(c4 * 4 + 0) * 33 + row] = v.x;
            xsT[(c4 * 4 + 1) * 33 + row] = v.y;
            xsT[(c4 * 4 + 2) * 33 + row] = v.z;
            xsT[(c4 * 4 + 3) * 33 + row] = v.w;
        }
        if (t < 32) maskc[t] = mask[m0 + t];
        __syncthreads();

        // --- logits for 12 h x 32 m + per-row online-softmax state update
        if (t < 384) {
            const int h = t >> 5, mloc = t & 31, m = m0 + mloc;
            float p0 = 0.f, p1 = 0.f, p2 = 0.f, p3 = 0.f;
            const float* wh = &w2sT[h * 128];
            const float* xc = &xsT[mloc];
#pragma unroll 8
            for (int c4 = 0; c4 < 32; ++c4) {
                float4 w = *(const float4*)(wh + c4 * 4);
                p0 += w.x * xc[(c4 * 4 + 0) * 33];
                p1 += w.y * xc[(c4 * 4 + 1) * 33];
                p2 += w.z * xc[(c4 * 4 + 2) * 33];
                p3 += w.w * xc[(c4 * 4 + 3) * 33];
            }
            const float a2d = (p0 + p1) + (p2 + p3);
            const float4* kt4 = (const float4*)(ktab + ((size_t)h * NN + m) * 32);
            const float4* qh  = (const float4*)&qt[h * 32];
            float qk0 = 0.f, qk1 = 0.f;
#pragma unroll
            for (int j = 0; j < 8; j += 2) {
                float4 a = qh[j],     b = kt4[j];
                float4 a2_ = qh[j+1], b2_ = kt4[j+1];
                qk0 += a.x * b.x + a.y * b.y + a.z * b.z + a.w * b.w;
                qk1 += a2_.x * b2_.x + a2_.y * b2_.y + a2_.z * b2_.z + a2_.w * b2_.w;
            }
            const float mval = -100000.f * (1.f - maskn * maskc[mloc]);
            const float l = (qk0 + qk1) + a2d + mval;
            pL[h * 1024 + m] = l;
            // half-wave (32-lane) butterfly reduce
            float cm = l;
#pragma unroll
            for (int off = 16; off; off >>= 1) cm = fmaxf(cm, __shfl_xor(cm, off));
            const float mOld = st_m[h];
            const float mNew = fmaxf(mOld, cm);
            const float pv = __expf(l - mNew);
            pe[h * 32 + mloc] = pv;
            float cs = pv;
#pragma unroll
            for (int off = 16; off; off >>= 1) cs += __shfl_xor(cs, off);
            if (mloc == 0) {
                const float r = __expf(mOld - mNew);  // 0 on first chunk
                st_s[h] = st_s[h] * r + cs;
                st_m[h] = mNew;
                resc[h] = r;
            }
        }
        __syncthreads();

        // --- online attn_2d accumulation (rescale regs, add pe-weighted chunk)
        {
            xa0 *= resc[hx];
            xa1 *= resc[hx + 4];
            xa2 *= resc[hx + 8];
            const float* xv = &xsT[cx * 33];
            const float* pA = &pe[hx * 32];
            const float* pB = &pe[(hx + 4) * 32];
            const float* pC = &pe[(hx + 8) * 32];
#pragma unroll 8
            for (int mm = 0; mm < 32; ++mm) {
                const float x_ = xv[mm];
                xa0 += pA[mm] * x_;
                xa1 += pB[mm] * x_;
                xa2 += pC[mm] * x_;
            }
        }
        __syncthreads();
    }

    // --- epilogue 1: normalized attention rows (coalesced f4)
#pragma unroll
    for (int rep = 0; rep < 6; ++rep) {
        const int task = t + (rep << 9);      // 0..3071 = 12h x 256 quads
        const int h = task >> 8, q4 = task & 255;
        const float M = st_m[h], invS = 1.f / st_s[h];
        float4 l4 = *(const float4*)&pL[h * 1024 + q4 * 4];
        float4 o;
        o.x = __expf(l4.x - M) * invS;
        o.y = __expf(l4.y - M) * invS;
        o.z = __expf(l4.z - M) * invS;
        o.w = __expf(l4.w - M) * invS;
        *(float4*)(attn + ((size_t)h * NN + n) * NN + q4 * 4) = o;
    }
    // --- epilogue 2: attn_2d block of fin
    const size_t fb = (size_t)n * FDIM + 576;
    fin[fb + (size_t)hx * 128 + cx]        = xa0 / st_s[hx];
    fin[fb + (size_t)(hx + 4) * 128 + cx]  = xa1 / st_s[hx + 4];
    fin[fb + (size_t)(hx + 8) * 128 + cx]  = xa2 / st_s[hx + 8];
}

// ---------------- 5: attn @ V as tiled GEMM (grid 12 h x 16 n-tiles) -------
__global__ __launch_bounds__(256) void attnv2_kernel(
    const float* __restrict__ attn, const float* __restrict__ vT,
    float* __restrict__ fin, float* __restrict__ resptg)
{
    __shared__ float As2[64 * 68];   // attn tile [n][m], pad 68 (16B-aligned rows)
    __shared__ float Vs[40 * 68];    // V tile [c][m]
    const int h = blockIdx.x, n0 = blockIdx.y * 64;
    const int t = threadIdx.x;
    const int tn = t >> 3, tc = t & 7;   // 32 n-pairs x 8 col-groups(5)
    float acc[2][5];
#pragma unroll
    for (int i = 0; i < 2; ++i)
#pragma unroll
        for (int j = 0; j < 5; ++j) acc[i][j] = 0.f;

    for (int mc = 0; mc < 16; ++mc) {
        const int m0 = mc * 64;
#pragma unroll
        for (int k = 0; k < 4; ++k) {
            const int f = t + (k << 8);     // 1024 f4 = 64 rows x 16
            const int row = f >> 4, q = f & 15;
            *(float4*)&As2[row * 68 + q * 4] =
                *(const float4*)(attn + ((size_t)h * NN + n0 + row) * NN + m0 + q * 4);
        }
        for (int f = t; f < 640; f += 256) { // 640 f4 = 40 rows x 16
            const int row = f >> 4, q = f & 15;
            const int rg = (row < 16) ? (h * 16 + row) : (192 + h * 24 + (row - 16));
            *(float4*)&Vs[row * 68 + q * 4] =
                *(const float4*)(vT + (size_t)rg * NN + m0 + q * 4);
        }
        __syncthreads();
#pragma unroll
        for (int q = 0; q < 16; ++q) {
            float4 a0 = *(const float4*)&As2[(tn * 2 + 0) * 68 + q * 4];
            float4 a1 = *(const float4*)&As2[(tn * 2 + 1) * 68 + q * 4];
#pragma unroll
            for (int j = 0; j < 5; ++j) {
                float4 vv = *(const float4*)&Vs[(tc * 5 + j) * 68 + q * 4];
                acc[0][j] += a0.x * vv.x + a0.y * vv.y + a0.z * vv.z + a0.w * vv.w;
                acc[1][j] += a1.x * vv.x + a1.y * vv.y + a1.z * vv.z + a1.w * vv.w;
            }
        }
        __syncthreads();
    }
#pragma unroll
    for (int i = 0; i < 2; ++i) {
        const int nn_ = n0 + tn * 2 + i;
#pragma unroll
        for (int j = 0; j < 5; ++j) {
            const int c = tc * 5 + j;
            if (c < 16) fin[(size_t)nn_ * FDIM + h * 16 + c] = acc[i][j];
            else        resptg[(size_t)nn_ * 288 + h * 24 + (c - 16)] = acc[i][j];
        }
    }
}

// ---------------- 6: invert point transform, dist, write into final --------
__global__ __launch_bounds__(128) void ptout_kernel(
    const float* __restrict__ resptg, const float* __restrict__ rot,
    const float* __restrict__ trans, float* __restrict__ fin)
{
    const int n = blockIdx.x, t = threadIdx.x;
    if (t >= 96) return;
    float g0 = resptg[(size_t)n * 288 + t * 3 + 0];
    float g1 = resptg[(size_t)n * 288 + t * 3 + 1];
    float g2 = resptg[(size_t)n * 288 + t * 3 + 2];
    float d0 = g0 - trans[n * 3 + 0];
    float d1 = g1 - trans[n * 3 + 1];
    float d2 = g2 - trans[n * 3 + 2];
    float l0 = rot[n * 9 + 0] * d0 + rot[n * 9 + 3] * d1 + rot[n * 9 + 6] * d2;
    float l1 = rot[n * 9 + 1] * d0 + rot[n * 9 + 4] * d1 + rot[n * 9 + 7] * d2;
    float l2 = rot[n * 9 + 2] * d0 + rot[n * 9 + 5] * d1 + rot[n * 9 + 8] * d2;
    const size_t base = (size_t)n * FDIM;
    fin[base + 192 + t] = l0;
    fin[base + 288 + t] = l1;
    fin[base + 384 + t] = l2;
    fin[base + 480 + t] = sqrtf(1e-8f + l0 * l0 + l1 * l1 + l2 * l2);
}

// ---------------- 7: final GEMM (K-split + atomics) ----------------
__global__ __launch_bounds__(256) void outgemm_kernel(
    const float* __restrict__ fin, const float* __restrict__ wout,
    const float* __restrict__ bout, float* __restrict__ out)
{
    const int n0 = blockIdx.x * 64;
    const int m0 = blockIdx.y * 128;
    const int z  = blockIdx.z;
    gemm_tile_128x64<true>(fin, wout, bout, out, FDIM, COUT, m0, n0, z * 352, 22, z == 0);
}

extern "C" void kernel_launch(void* const* d_in, const int* in_sizes, int n_in,
                              void* d_out, int out_size, void* d_ws, size_t ws_size,
                              hipStream_t stream)
{
    const float* in1d  = (const float*)d_in[0];
    const float* in2d  = (const float*)d_in[1];
    const float* mask  = (const float*)d_in[2];
    const float* rot   = (const float*)d_in[3];
    const float* trans = (const float*)d_in[4];
    const float* wqs   = (const float*)d_in[5];
    const float* bqs   = (const float*)d_in[6];
    const float* wkvs  = (const float*)d_in[7];
    const float* bkvs  = (const float*)d_in[8];
    const float* wqp   = (const float*)d_in[9];
    const float* bqp   = (const float*)d_in[10];
    const float* bkvpW = (const float*)d_in[11]; // w_kv_point
    const float* bkvpB = (const float*)d_in[12]; // b_kv_point
    const float* w2d   = (const float*)d_in[13];
    const float* b2d   = (const float*)d_in[14];
    const float* tpw   = (const float*)d_in[15];
    const float* wout  = (const float*)d_in[16];
    const float* bout  = (const float*)d_in[17];

    float* ws     = (float*)d_ws;
    float* qs     = ws + OFF_QS;
    float* kvs    = ws + OFF_KVS;
    float* qpf    = ws + OFF_QPF;
    float* kvpf   = ws + OFF_KVPF;
    float* qptg   = ws + OFF_QPTG;
    float* kvptg  = ws + OFF_KVPTG;
    float* q2     = ws + OFF_Q2;
    float* k2     = ws + OFF_K2;
    float* pw     = ws + OFF_PW;
    float* vT     = ws + OFF_VT;
    float* resptg = ws + OFF_RESPTG;
    float* fin    = ws + OFF_FINAL;
    float* attn   = ws + OFF_LOGITS;
    float* ktab   = ws + OFF_KTAB;

    hipMemsetAsync(d_out, 0, (size_t)out_size * sizeof(float), stream);

    proj_kernel<<<152, 256, 0, stream>>>(in1d, wqs, bqs, wkvs, bkvs, wqp, bqp, bkvpW, bkvpB,
                                         qs, kvs, qpf, kvpf);
    points_kernel<<<NN, 192, 0, stream>>>(qpf, kvpf, rot, trans, tpw, qptg, kvptg, q2, k2, pw);
    vt_kernel<<<1920, 256, 0, stream>>>(kvs, kvptg, vT);
    tab_kernel<<<48, 256, 0, stream>>>(kvs, kvptg, k2, pw, ktab);
    fused_kernel<<<NN, 512, 0, stream>>>(in2d, w2d, b2d, mask, qs, qptg, q2, pw,
                                         ktab, attn, fin);
    attnv2_kernel<<<dim3(HH, 16), 256, 0, stream>>>(attn, vT, fin, resptg);
    ptout_kernel<<<NN, 128, 0, stream>>>(resptg, rot, trans, fin);
    outgemm_kernel<<<dim3(6, 8, 6), 256, 0, stream>>>(fin, wout, bout, (float*)d_out);
}